// Round 3
// baseline (152.550 us; speedup 1.0000x reference)
//
#include <hip/hip_runtime.h>
#include <math.h>

// Problem constants
#define NN   768
#define HH   300
#define HPAD 320          // h rows allocated (k1 tiles of 32 x 10)
#define KD   768

// ---- ws float layout (all [h][i] "transposed": row = h, 768 i per row) ----
// CF_t[320][768] = hx^T                    @ 0
// AF_t[320][768] = (hy[perm]+b1)^T        @ 245760
// SP  [4][768][768] pairwise h-partials    @ 491520
// ES  esum[768]                            @ 2850816
// T0P t0[768]                              @ 2851584
#define CF_OFF  0
#define AF_OFF  245760
#define SP_OFF  491520
#define SP_STR  589824
#define ES_OFF  2850816
#define T0_OFF  2851584

// ============ K1: both GEMMs, transposed out, full K, bias fused ============
// out[h][i] = sum_k W1[h][koff+k] * src[i][k]  (+ b1[h] for gemm 1)
// tile 32h x 64i, per-thread 2h x 4i, grid (12 i, 10 h, 2 gemm) = 240 blocks.
__global__ __launch_bounds__(256) void k1_gemm(
    const float* __restrict__ x, const float* __restrict__ y,
    const int* __restrict__ perm, const float* __restrict__ W1,
    const float* __restrict__ b1, float* __restrict__ wsf)
{
    const int tid = threadIdx.x;
    const int tx = tid & 15;           // i: 4tx..4tx+3
    const int ty = tid >> 4;           // h: 2ty..2ty+1
    const int i0 = blockIdx.x * 64;
    const int h0 = blockIdx.y * 32;
    const int g  = blockIdx.z;         // 0: hx from x, 1: hy[perm] from y

    const float* src = g ? y : x;

    __shared__ float Xt[32][66];       // Xt[k][i]
    __shared__ float Wt[32][34];       // Wt[k][h]

    float4 acc0 = make_float4(0.f,0.f,0.f,0.f);
    float4 acc1 = make_float4(0.f,0.f,0.f,0.f);

    // staging maps
    const int kq = (tid & 7) << 2;     // k quad within 32
    int r0 = i0 + (tid >> 3);          // x rows 0..31
    int r1 = r0 + 32;                  // x rows 32..63
    if (g) { r0 = perm[r0]; r1 = perm[r1]; }
    const float* xp0 = src + (size_t)r0 * KD + kq;
    const float* xp1 = src + (size_t)r1 * KD + kq;
    const int wrow = tid >> 3;         // 0..31
    const int hg = h0 + wrow;
    const float* wp = W1 + (size_t)hg * (2*KD) + (g ? KD : 0) + kq;
    const bool hvalid = hg < HH;

    for (int kb = 0; kb < KD; kb += 32) {
        float4 v0 = *(const float4*)(xp0 + kb);
        float4 v1 = *(const float4*)(xp1 + kb);
        float4 w  = make_float4(0.f,0.f,0.f,0.f);
        if (hvalid) w = *(const float4*)(wp + kb);
        __syncthreads();               // protect prior-iter readers
        Xt[kq+0][tid>>3]      = v0.x; Xt[kq+1][tid>>3]      = v0.y;
        Xt[kq+2][tid>>3]      = v0.z; Xt[kq+3][tid>>3]      = v0.w;
        Xt[kq+0][32+(tid>>3)] = v1.x; Xt[kq+1][32+(tid>>3)] = v1.y;
        Xt[kq+2][32+(tid>>3)] = v1.z; Xt[kq+3][32+(tid>>3)] = v1.w;
        Wt[kq+0][wrow] = w.x; Wt[kq+1][wrow] = w.y;
        Wt[kq+2][wrow] = w.z; Wt[kq+3][wrow] = w.w;
        __syncthreads();

        #pragma unroll 8
        for (int k = 0; k < 32; ++k) {
            float2 a = *(const float2*)&Wt[k][2*ty];
            float4 b = *(const float4*)&Xt[k][4*tx];
            acc0.x = fmaf(a.x,b.x,acc0.x); acc0.y = fmaf(a.x,b.y,acc0.y);
            acc0.z = fmaf(a.x,b.z,acc0.z); acc0.w = fmaf(a.x,b.w,acc0.w);
            acc1.x = fmaf(a.y,b.x,acc1.x); acc1.y = fmaf(a.y,b.y,acc1.y);
            acc1.z = fmaf(a.y,b.z,acc1.z); acc1.w = fmaf(a.y,b.w,acc1.w);
        }
    }

    float* dstBase = wsf + (g ? AF_OFF : CF_OFF);
    #pragma unroll
    for (int r = 0; r < 2; ++r) {
        int hh = h0 + 2*ty + r;
        float bias = (g && hh < HH) ? b1[hh] : 0.f;
        float4 o = (r == 0) ? acc0 : acc1;
        o.x += bias; o.y += bias; o.z += bias; o.w += bias;
        *(float4*)(dstBase + (size_t)hh * NN + i0 + 4*tx) = o;
    }
}

// ======== K2: pairwise relu-dot h-partials, chunks of 75 ====================
// tile 96i x 48j, per-thread 6i x 3j, grid (16 j, 8 i, 4 p) = 512 = 2/CU.
__global__ __launch_bounds__(256) void k2_pair(
    const float* __restrict__ wsf, const float* __restrict__ w2,
    float* __restrict__ sp)
{
    const int tid = threadIdx.x;
    const int tx = tid & 15;           // j: {2tx,2tx+1} u {32+tx}
    const int ty = tid >> 4;           // i: {4ty..4ty+3} u {64+2ty,65+2ty}
    const int j0 = blockIdx.x * 48;
    const int i0 = blockIdx.y * 96;
    const int p  = blockIdx.z;
    const int h0 = p * 75;

    const float* AF = wsf + AF_OFF;
    const float* CF = wsf + CF_OFF;

    __shared__ float As[75][100];      // As[h][i], stride 100 staggers banks
    __shared__ float Cs[75][48];       // Cs[h][j]
    __shared__ float w2s[75];

    // stage A: 75 h-rows x 96 i = 1800 float4 (coalesced rows of AF_t)
    for (int e = tid; e < 1800; e += 256) {
        int h = e / 24, q = (e % 24) * 4;
        float4 v = *(const float4*)(AF + (size_t)(h0 + h) * NN + i0 + q);
        *(float4*)&As[h][q] = v;
    }
    // stage C: 75 x 48 = 900 float4
    for (int e = tid; e < 900; e += 256) {
        int h = e / 12, q = (e % 12) * 4;
        float4 v = *(const float4*)(CF + (size_t)(h0 + h) * NN + j0 + q);
        *(float4*)&Cs[h][q] = v;
    }
    if (tid < 75) w2s[tid] = w2[h0 + tid];
    __syncthreads();

    float acc[6][3];
    #pragma unroll
    for (int r = 0; r < 6; ++r)
        #pragma unroll
        for (int c = 0; c < 3; ++c) acc[r][c] = 0.f;

    #pragma unroll 5
    for (int h = 0; h < 75; ++h) {
        float wh = w2s[h];
        float4 a0 = *(const float4*)&As[h][4*ty];
        float2 a1 = *(const float2*)&As[h][64 + 2*ty];
        float2 c0 = *(const float2*)&Cs[h][2*tx];
        float  c2 = Cs[h][32 + tx];
        float ar[6] = {a0.x, a0.y, a0.z, a0.w, a1.x, a1.y};
        float cr[3] = {c0.x, c0.y, c2};
        #pragma unroll
        for (int r = 0; r < 6; ++r) {
            #pragma unroll
            for (int c = 0; c < 3; ++c) {
                float t = fmaxf(ar[r] + cr[c], 0.f);
                acc[r][c] = fmaf(t, wh, acc[r][c]);
            }
        }
    }

    float* dst = sp + (size_t)p * SP_STR;
    #pragma unroll
    for (int r = 0; r < 6; ++r) {
        int i = i0 + ((r < 4) ? (4*ty + r) : (64 + 2*ty + (r - 4)));
        float* rp = dst + (size_t)i * NN + j0;
        *(float2*)(rp + 2*tx) = make_float2(acc[r][0], acc[r][1]);
        rp[32 + tx] = acc[r][2];
    }
}

// ==== K2e: blocks 0..767: combine partials + exp-rowsum; 768..770: t0 =======
__global__ __launch_bounds__(256) void k2e_rows(
    const float* __restrict__ wsf, const int* __restrict__ perm,
    const float* __restrict__ w2, const float* __restrict__ b2,
    float* __restrict__ esum, float* __restrict__ t0out)
{
    const int tid = threadIdx.x;
    const float b2v = b2[0];

    if ((int)blockIdx.x < NN) {
        __shared__ float red[256];
        const int row = blockIdx.x;
        const float* spr = wsf + SP_OFF + (size_t)row * NN;
        float e = 0.f;
        #pragma unroll
        for (int jj = 0; jj < 3; ++jj) {
            int j = tid + jj * 256;
            float s = spr[j];
            s += spr[(size_t)1 * SP_STR + j];
            s += spr[(size_t)2 * SP_STR + j];
            s += spr[(size_t)3 * SP_STR + j];
            e += expf(s + b2v);
        }
        red[tid] = e;
        __syncthreads();
        for (int s = 128; s > 0; s >>= 1) {
            if (tid < s) red[tid] += red[tid + s];
            __syncthreads();
        }
        if (tid == 0) esum[row] = red[0];
    } else {
        // t0 for 768 columns: col i pairs (x_{perm[i]}, y_{perm[i]})
        const int col = ((int)blockIdx.x - NN) * 256 + tid;
        const int pcol = perm[col];
        const float* AF = wsf + AF_OFF;
        const float* CF = wsf + CF_OFF;
        float s = 0.f;
        for (int h = 0; h < HH; ++h) {
            float a = AF[(size_t)h * NN + col];    // coalesced
            float c = CF[(size_t)h * NN + pcol];   // gather (L2-resident)
            float z = fmaxf(a + c, 0.f);
            s = fmaf(z, w2[h], s);
        }
        float u = s + b2v;
        t0out[col] = (u > 0.f) ? u + log1pf(expf(-u)) : log1pf(expf(u));
    }
}

// ================= K3: final double-precision reduction =====================
__global__ __launch_bounds__(256) void k3_final(
    const float* __restrict__ wsf, float* __restrict__ out)
{
    const int tid = threadIdx.x;
    const float* esum = wsf + ES_OFF;
    const float* t0   = wsf + T0_OFF;

    double st0 = 0.0, slse = 0.0;
    for (int i = tid; i < NN; i += 256) {
        st0  += (double)t0[i];
        slse += log((double)NN + (double)esum[i]);
    }
    __shared__ double sa[256], sb[256];
    sa[tid] = st0; sb[tid] = slse;
    __syncthreads();
    for (int s = 128; s > 0; s >>= 1) {
        if (tid < s) { sa[tid] += sa[tid+s]; sb[tid] += sb[tid+s]; }
        __syncthreads();
    }
    if (tid == 0) {
        double lb = sa[0]/(double)NN - (sb[0]/(double)NN - log((double)NN));
        out[0] = (float)lb;
    }
}

extern "C" void kernel_launch(void* const* d_in, const int* in_sizes, int n_in,
                              void* d_out, int out_size, void* d_ws, size_t ws_size,
                              hipStream_t stream) {
    const float* x    = (const float*)d_in[0];
    const float* y    = (const float*)d_in[1];
    const int*   perm = (const int*)  d_in[2];
    const float* W1   = (const float*)d_in[3];
    const float* b1   = (const float*)d_in[4];
    const float* W2   = (const float*)d_in[5];
    const float* b2   = (const float*)d_in[6];
    float* wsf = (float*)d_ws;
    float* out = (float*)d_out;

    k1_gemm  <<<dim3(12,10,2), 256, 0, stream>>>(x, y, perm, W1, b1, wsf);
    k2_pair  <<<dim3(16,8,4),  256, 0, stream>>>(wsf, W2, wsf + SP_OFF);
    k2e_rows <<<NN + 3,        256, 0, stream>>>(wsf, perm, W2, b2,
                                                 wsf + ES_OFF, wsf + T0_OFF);
    k3_final <<<1,             256, 0, stream>>>(wsf, out);
}

// Round 4
// 135.250 us; speedup vs baseline: 1.1279x; 1.1279x over previous
//
#include <hip/hip_runtime.h>
#include <math.h>

// Problem constants
#define NN   768
#define HH   300
#define HPAD 320          // h rows allocated (5 tiles x 64)
#define KD   768

// ---- ws float layout (matrices stored [h][i], 768 i per row) ----
// P:  [2 g][8 ks][320][768] gemm partials  @ 0
// CF_t[320][768] = hx^T                    @ 3932160
// AF_t[320][768] = (hy[perm]+b1)^T         @ 4177920
// SP  [4][768][768] pairwise h-partials    @ 4423680
// ES  esum[768]                            @ 6782976
// T0  t0[768]                              @ 6783744
#define P_OFF    0
#define PKS_STR  245760           // 320*768
#define PG_STR   1966080          // 8*PKS_STR
#define CF_OFF   3932160
#define AF_OFF   4177920
#define SP_OFF   4423680
#define SP_STR   589824
#define ES_OFF   6782976
#define T0_OFF   6783744

// ========== K1: both GEMMs, transposed out, fat tile, K-split 8 =============
// P[g][ks][h][i] = sum_{k in slice} W1[h][koff+k] * src[row(i)][k]
// tile 64h x 128i, per-thread 4h x 8i (32 accs), Kc=96, 256 threads.
// grid (6 i, 5 h, 16 = g*8+ks) = 480 blocks = 7.5 waves/CU.
__global__ __launch_bounds__(256) void k1_gemm(
    const float* __restrict__ x, const float* __restrict__ y,
    const int* __restrict__ perm, const float* __restrict__ W1,
    float* __restrict__ wsf)
{
    const int tid = threadIdx.x;
    const int tx = tid & 15;          // i: {4tx..4tx+3} u {64+4tx..}
    const int ty = tid >> 4;          // h: 4ty..4ty+3
    const int i0 = blockIdx.x * 128;
    const int h0 = blockIdx.y * 64;
    const int g  = blockIdx.z & 1;
    const int ks = blockIdx.z >> 1;
    const int kbeg = ks * 96;

    const float* src = g ? y : x;
    const int koff = g ? KD : 0;

    __shared__ float Xt[32][132];     // Xt[k][i], 128 i + pad (16B-aligned rows)
    __shared__ float Wt[32][68];      // Wt[k][h], 64 h + pad

    float4 acc[4][2];
    #pragma unroll
    for (int r = 0; r < 4; ++r) { acc[r][0] = make_float4(0,0,0,0);
                                  acc[r][1] = make_float4(0,0,0,0); }

    // hoisted staging addresses (perm gather done once)
    const int kq = (tid & 7) << 2;
    const float* xp[4];
    int xr[4];
    #pragma unroll
    for (int it = 0; it < 4; ++it) {
        int row = ((tid + it*256) >> 3);          // 0..127
        int gr = i0 + row;
        if (g) gr = perm[gr];
        xp[it] = src + (size_t)gr * KD + kbeg + kq;
        xr[it] = row;
    }
    const float* wp[2];
    int wr[2]; bool wv[2];
    #pragma unroll
    for (int it = 0; it < 2; ++it) {
        int hrow = ((tid + it*256) >> 3);         // 0..63
        int hg = h0 + hrow;
        wv[it] = hg < HH;
        wp[it] = W1 + (size_t)(wv[it] ? hg : 0) * (2*KD) + koff + kbeg + kq;
        wr[it] = hrow;
    }

    for (int kb = 0; kb < 96; kb += 32) {
        float4 xv[4], wvv[2];
        #pragma unroll
        for (int it = 0; it < 4; ++it) xv[it] = *(const float4*)(xp[it] + kb);
        #pragma unroll
        for (int it = 0; it < 2; ++it) {
            wvv[it] = *(const float4*)(wp[it] + kb);
            if (!wv[it]) wvv[it] = make_float4(0,0,0,0);
        }
        if (kb) __syncthreads();
        #pragma unroll
        for (int it = 0; it < 4; ++it) {
            Xt[kq+0][xr[it]] = xv[it].x; Xt[kq+1][xr[it]] = xv[it].y;
            Xt[kq+2][xr[it]] = xv[it].z; Xt[kq+3][xr[it]] = xv[it].w;
        }
        #pragma unroll
        for (int it = 0; it < 2; ++it) {
            Wt[kq+0][wr[it]] = wvv[it].x; Wt[kq+1][wr[it]] = wvv[it].y;
            Wt[kq+2][wr[it]] = wvv[it].z; Wt[kq+3][wr[it]] = wvv[it].w;
        }
        __syncthreads();

        #pragma unroll 8
        for (int k = 0; k < 32; ++k) {
            float4 a  = *(const float4*)&Wt[k][4*ty];
            float4 b0 = *(const float4*)&Xt[k][4*tx];
            float4 b1v = *(const float4*)&Xt[k][64 + 4*tx];
            float ar[4] = {a.x, a.y, a.z, a.w};
            #pragma unroll
            for (int r = 0; r < 4; ++r) {
                acc[r][0].x = fmaf(ar[r], b0.x,  acc[r][0].x);
                acc[r][0].y = fmaf(ar[r], b0.y,  acc[r][0].y);
                acc[r][0].z = fmaf(ar[r], b0.z,  acc[r][0].z);
                acc[r][0].w = fmaf(ar[r], b0.w,  acc[r][0].w);
                acc[r][1].x = fmaf(ar[r], b1v.x, acc[r][1].x);
                acc[r][1].y = fmaf(ar[r], b1v.y, acc[r][1].y);
                acc[r][1].z = fmaf(ar[r], b1v.z, acc[r][1].z);
                acc[r][1].w = fmaf(ar[r], b1v.w, acc[r][1].w);
            }
        }
    }

    float* dst = wsf + P_OFF + (size_t)(g*8 + ks) * PKS_STR;
    #pragma unroll
    for (int r = 0; r < 4; ++r) {
        float* rp = dst + (size_t)(h0 + 4*ty + r) * NN + i0;
        *(float4*)(rp + 4*tx)      = acc[r][0];
        *(float4*)(rp + 64 + 4*tx) = acc[r][1];
    }
}

// ===== K1b: sum 8 K-partials -> CF_t/AF_t; A += b1; pad h-rows -> 0 =========
__global__ __launch_bounds__(256) void k1b_combine(
    const float* __restrict__ b1, float* __restrict__ wsf)
{
    int idx = blockIdx.x * 256 + threadIdx.x;   // 480 blocks -> 122880
    int g = idx >= 61440;
    int rem = idx - g * 61440;
    int h = rem / 192;
    int i4 = (rem % 192) * 4;

    float4 o = make_float4(0.f,0.f,0.f,0.f);
    if (h < HH) {
        const float* p = wsf + P_OFF + (size_t)g * PG_STR + (size_t)h * NN + i4;
        #pragma unroll
        for (int ks = 0; ks < 8; ++ks) {
            float4 v = *(const float4*)(p + (size_t)ks * PKS_STR);
            o.x += v.x; o.y += v.y; o.z += v.z; o.w += v.w;
        }
        if (g) {
            float bv = b1[h];
            o.x += bv; o.y += bv; o.z += bv; o.w += bv;
        }
    }
    float* dst = wsf + (g ? AF_OFF : CF_OFF) + (size_t)h * NN + i4;
    *(float4*)dst = o;
}

// ======== K2: pairwise relu-dot h-partials, chunks of 75 ====================
// tile 96i x 48j, per-thread 6i x 3j, grid (16 j, 8 i, 4 p) = 512 = 2/CU.
__global__ __launch_bounds__(256) void k2_pair(
    const float* __restrict__ wsf, const float* __restrict__ w2,
    float* __restrict__ sp)
{
    const int tid = threadIdx.x;
    const int tx = tid & 15;           // j: {2tx,2tx+1} u {32+tx}
    const int ty = tid >> 4;           // i: {4ty..4ty+3} u {64+2ty,65+2ty}
    const int j0 = blockIdx.x * 48;
    const int i0 = blockIdx.y * 96;
    const int p  = blockIdx.z;
    const int h0 = p * 75;

    const float* AF = wsf + AF_OFF;
    const float* CF = wsf + CF_OFF;

    __shared__ float As[75][100];      // As[h][i]
    __shared__ float Cs[75][48];       // Cs[h][j]
    __shared__ float w2s[75];

    for (int e = tid; e < 1800; e += 256) {
        int h = e / 24, q = (e % 24) * 4;
        float4 v = *(const float4*)(AF + (size_t)(h0 + h) * NN + i0 + q);
        *(float4*)&As[h][q] = v;
    }
    for (int e = tid; e < 900; e += 256) {
        int h = e / 12, q = (e % 12) * 4;
        float4 v = *(const float4*)(CF + (size_t)(h0 + h) * NN + j0 + q);
        *(float4*)&Cs[h][q] = v;
    }
    if (tid < 75) w2s[tid] = w2[h0 + tid];
    __syncthreads();

    float acc[6][3];
    #pragma unroll
    for (int r = 0; r < 6; ++r)
        #pragma unroll
        for (int c = 0; c < 3; ++c) acc[r][c] = 0.f;

    #pragma unroll 5
    for (int h = 0; h < 75; ++h) {
        float wh = w2s[h];
        float4 a0 = *(const float4*)&As[h][4*ty];
        float2 a1 = *(const float2*)&As[h][64 + 2*ty];
        float2 c0 = *(const float2*)&Cs[h][2*tx];
        float  c2 = Cs[h][32 + tx];
        float ar[6] = {a0.x, a0.y, a0.z, a0.w, a1.x, a1.y};
        float cr[3] = {c0.x, c0.y, c2};
        #pragma unroll
        for (int r = 0; r < 6; ++r) {
            #pragma unroll
            for (int c = 0; c < 3; ++c) {
                float t = fmaxf(ar[r] + cr[c], 0.f);
                acc[r][c] = fmaf(t, wh, acc[r][c]);
            }
        }
    }

    float* dst = sp + (size_t)p * SP_STR;
    #pragma unroll
    for (int r = 0; r < 6; ++r) {
        int i = i0 + ((r < 4) ? (4*ty + r) : (64 + 2*ty + (r - 4)));
        float* rp = dst + (size_t)i * NN + j0;
        *(float2*)(rp + 2*tx) = make_float2(acc[r][0], acc[r][1]);
        rp[32 + tx] = acc[r][2];
    }
}

// ==== K2e: blocks 0..767: combine partials + exp-rowsum; 768..770: t0 =======
__global__ __launch_bounds__(256) void k2e_rows(
    const float* __restrict__ wsf, const int* __restrict__ perm,
    const float* __restrict__ w2, const float* __restrict__ b2,
    float* __restrict__ esum, float* __restrict__ t0out)
{
    const int tid = threadIdx.x;
    const float b2v = b2[0];

    if ((int)blockIdx.x < NN) {
        __shared__ float red[256];
        const int row = blockIdx.x;
        const float* spr = wsf + SP_OFF + (size_t)row * NN;
        float e = 0.f;
        #pragma unroll
        for (int jj = 0; jj < 3; ++jj) {
            int j = tid + jj * 256;
            float s = spr[j];
            s += spr[(size_t)1 * SP_STR + j];
            s += spr[(size_t)2 * SP_STR + j];
            s += spr[(size_t)3 * SP_STR + j];
            e += expf(s + b2v);
        }
        red[tid] = e;
        __syncthreads();
        for (int s = 128; s > 0; s >>= 1) {
            if (tid < s) red[tid] += red[tid + s];
            __syncthreads();
        }
        if (tid == 0) esum[row] = red[0];
    } else {
        // t0 over columns: col i holds sample perm[i]; sum over bijection = sum t0
        const int col = ((int)blockIdx.x - NN) * 256 + tid;
        const int pcol = perm[col];
        const float* AF = wsf + AF_OFF;
        const float* CF = wsf + CF_OFF;
        float s = 0.f;
        for (int h = 0; h < HH; ++h) {
            float a = AF[(size_t)h * NN + col];    // coalesced
            float c = CF[(size_t)h * NN + pcol];   // gather (L2-resident)
            float z = fmaxf(a + c, 0.f);
            s = fmaf(z, w2[h], s);
        }
        float u = s + b2v;
        t0out[col] = (u > 0.f) ? u + log1pf(expf(-u)) : log1pf(expf(u));
    }
}

// ================= K3: final double-precision reduction =====================
__global__ __launch_bounds__(256) void k3_final(
    const float* __restrict__ wsf, float* __restrict__ out)
{
    const int tid = threadIdx.x;
    const float* esum = wsf + ES_OFF;
    const float* t0   = wsf + T0_OFF;

    double st0 = 0.0, slse = 0.0;
    for (int i = tid; i < NN; i += 256) {
        st0  += (double)t0[i];
        slse += log((double)NN + (double)esum[i]);
    }
    __shared__ double sa[256], sb[256];
    sa[tid] = st0; sb[tid] = slse;
    __syncthreads();
    for (int s = 128; s > 0; s >>= 1) {
        if (tid < s) { sa[tid] += sa[tid+s]; sb[tid] += sb[tid+s]; }
        __syncthreads();
    }
    if (tid == 0) {
        double lb = sa[0]/(double)NN - (sb[0]/(double)NN - log((double)NN));
        out[0] = (float)lb;
    }
}

extern "C" void kernel_launch(void* const* d_in, const int* in_sizes, int n_in,
                              void* d_out, int out_size, void* d_ws, size_t ws_size,
                              hipStream_t stream) {
    const float* x    = (const float*)d_in[0];
    const float* y    = (const float*)d_in[1];
    const int*   perm = (const int*)  d_in[2];
    const float* W1   = (const float*)d_in[3];
    const float* b1   = (const float*)d_in[4];
    const float* W2   = (const float*)d_in[5];
    const float* b2   = (const float*)d_in[6];
    float* wsf = (float*)d_ws;
    float* out = (float*)d_out;

    k1_gemm    <<<dim3(6,5,16), 256, 0, stream>>>(x, y, perm, W1, wsf);
    k1b_combine<<<480,          256, 0, stream>>>(b1, wsf);
    k2_pair    <<<dim3(16,8,4), 256, 0, stream>>>(wsf, W2, wsf + SP_OFF);
    k2e_rows   <<<NN + 3,       256, 0, stream>>>(wsf, perm, W2, b2,
                                                  wsf + ES_OFF, wsf + T0_OFF);
    k3_final   <<<1,            256, 0, stream>>>(wsf, out);
}